// Round 5
// baseline (53.707 us; speedup 1.0000x reference)
//
#include <hip/hip_runtime.h>
#include <hip/hip_fp16.h>

// skipgram negative-sampling loss, MI355X.
// Phase 1: stream-convert v_emb f32 -> fp16 into d_ws (halves gather bytes AND
//          128B-line transactions per row: 512B->256B rows). Values ~±0.004,
//          fp16 rel err 2^-11 -> loss error ~1e-7, threshold is 2.8e-2.
// Phase 2: row-PAIR per wave (lanes 0-31 row 2p, lanes 32-63 row 2p+1), each
//          lane loads uint2 (4 halves, 8B) -> one VMEM instr covers both rows.
//          neg_score sums over K before logsigmoid -> accumulate the 20 neg
//          rows elementwise, one dot. Block reduce -> 2048 atomics.
// Rationale: R2-R4 all plateau at FETCH~85MB / ~2.1TB/s / ~41us regardless of
// structure -> random-granule L2-fill wall; only lever left is bytes/transactions.

constexpr int DIM  = 128;
constexpr int KNEG = 20;
constexpr int WAVES_PER_BLOCK = 4;

__device__ __forceinline__ float log_sigmoid(float x) {
    return fminf(x, 0.0f) - log1pf(__expf(-fabsf(x)));
}

// ---------- phase 1: f32 -> fp16 table ----------
__global__ __launch_bounds__(256) void convert_kernel(
    const float* __restrict__ src, unsigned int* __restrict__ dst2, int n4)
{
    int i = blockIdx.x * blockDim.x + threadIdx.x;
    const int stride = gridDim.x * blockDim.x;
    const float4* s4 = reinterpret_cast<const float4*>(src);
    uint2* d = reinterpret_cast<uint2*>(dst2);
    for (; i < n4; i += stride) {
        float4 v = s4[i];
        __half2 h0 = __floats2half2_rn(v.x, v.y);
        __half2 h1 = __floats2half2_rn(v.z, v.w);
        uint2 o;
        o.x = *reinterpret_cast<unsigned int*>(&h0);
        o.y = *reinterpret_cast<unsigned int*>(&h1);
        d[i] = o;
    }
}

__device__ __forceinline__ float2 h2f(unsigned int w) {
    __half2 h = *reinterpret_cast<__half2*>(&w);
    return __half22float2(h);
}

// ---------- phase 2: gather + loss (fp16 v-table) ----------
__global__ __launch_bounds__(256) void skipgram_half_kernel(
    const float* __restrict__ u_emb, const __half* __restrict__ v_half,
    const int* __restrict__ u_pos, const int* __restrict__ v_pos,
    const int* __restrict__ v_neg, float* __restrict__ out,
    int B, float neg_inv_b)
{
    const int lane  = threadIdx.x & 63;
    const int wslot = threadIdx.x >> 6;
    const int half  = lane >> 5;
    const int l32   = lane & 31;
    const int pair  = blockIdx.x * WAVES_PER_BLOCK + wslot;
    const int row   = pair * 2 + half;

    float contrib = 0.0f;

    if (row < B) {
        const int up = u_pos[row];
        const int vp = v_pos[row];
        const int4* nidx4 = reinterpret_cast<const int4*>(v_neg + (size_t)row * KNEG);
        int4 iv[5];
        #pragma unroll
        for (int q = 0; q < 5; ++q) iv[q] = nidx4[q];
        int idx[KNEG];
        #pragma unroll
        for (int q = 0; q < 5; ++q) {
            idx[q * 4 + 0] = iv[q].x; idx[q * 4 + 1] = iv[q].y;
            idx[q * 4 + 2] = iv[q].z; idx[q * 4 + 3] = iv[q].w;
        }

        // u row stays f32: lane covers dims [4*l32, 4*l32+4)
        const float4 uu = reinterpret_cast<const float4*>(u_emb + (size_t)up * DIM)[l32];
        // v rows fp16: uint2 = 4 halves = same 4 dims
        uint2 vvh = reinterpret_cast<const uint2*>(v_half + (size_t)vp * DIM)[l32];
        uint2 nh[KNEG];
        #pragma unroll
        for (int k = 0; k < KNEG; ++k)
            nh[k] = reinterpret_cast<const uint2*>(v_half + (size_t)idx[k] * DIM)[l32];

        __builtin_amdgcn_sched_barrier(0);

        float2 v0 = h2f(vvh.x), v1 = h2f(vvh.y);
        float pos = fmaf(uu.x, v0.x, fmaf(uu.y, v0.y, fmaf(uu.z, v1.x, uu.w * v1.y)));

        float ax = 0.0f, ay = 0.0f, az = 0.0f, aw = 0.0f;
        #pragma unroll
        for (int k = 0; k < KNEG; ++k) {
            float2 f0 = h2f(nh[k].x), f1 = h2f(nh[k].y);
            ax += f0.x; ay += f0.y; az += f1.x; aw += f1.y;
        }
        float neg = fmaf(uu.x, ax, fmaf(uu.y, ay, fmaf(uu.z, az, uu.w * aw)));

        #pragma unroll
        for (int off = 16; off; off >>= 1) {
            pos += __shfl_xor(pos, off);
            neg += __shfl_xor(neg, off);
        }

        float loss = log_sigmoid(pos) + log_sigmoid(-neg);
        contrib = (l32 == 0) ? loss : 0.0f;
    }

    contrib += __shfl_xor(contrib, 32);

    __shared__ float wsum[WAVES_PER_BLOCK];
    if (lane == 0) wsum[wslot] = contrib;
    __syncthreads();
    if (threadIdx.x == 0) {
        float s = 0.0f;
        #pragma unroll
        for (int w = 0; w < WAVES_PER_BLOCK; ++w) s += wsum[w];
        atomicAdd(out, s * neg_inv_b);
    }
}

// ---------- fallback (f32 gathers, R3 structure) if ws too small ----------
__global__ __launch_bounds__(256) void skipgram_f32_kernel(
    const float* __restrict__ u_emb, const float* __restrict__ v_emb,
    const int* __restrict__ u_pos, const int* __restrict__ v_pos,
    const int* __restrict__ v_neg, float* __restrict__ out,
    int B, float neg_inv_b)
{
    const int lane  = threadIdx.x & 63;
    const int wslot = threadIdx.x >> 6;
    const int half  = lane >> 5;
    const int l32   = lane & 31;
    const int pair  = blockIdx.x * WAVES_PER_BLOCK + wslot;
    const int row   = pair * 2 + half;

    float contrib = 0.0f;
    if (row < B) {
        const int up = u_pos[row];
        const int vp = v_pos[row];
        int idx[KNEG];
        #pragma unroll
        for (int k = 0; k < KNEG; ++k) idx[k] = v_neg[row * KNEG + k];
        const float4 uu = reinterpret_cast<const float4*>(u_emb + (size_t)up * DIM)[l32];
        const float4 vv = reinterpret_cast<const float4*>(v_emb + (size_t)vp * DIM)[l32];
        float pos = fmaf(uu.x, vv.x, fmaf(uu.y, vv.y, fmaf(uu.z, vv.z, uu.w * vv.w)));
        float ax = 0, ay = 0, az = 0, aw = 0;
        #pragma unroll
        for (int k = 0; k < KNEG; ++k) {
            float4 nv = reinterpret_cast<const float4*>(v_emb + (size_t)idx[k] * DIM)[l32];
            ax += nv.x; ay += nv.y; az += nv.z; aw += nv.w;
        }
        float neg = fmaf(uu.x, ax, fmaf(uu.y, ay, fmaf(uu.z, az, uu.w * aw)));
        #pragma unroll
        for (int off = 16; off; off >>= 1) {
            pos += __shfl_xor(pos, off);
            neg += __shfl_xor(neg, off);
        }
        float loss = log_sigmoid(pos) + log_sigmoid(-neg);
        contrib = (l32 == 0) ? loss : 0.0f;
    }
    contrib += __shfl_xor(contrib, 32);
    __shared__ float wsum[WAVES_PER_BLOCK];
    if (lane == 0) wsum[wslot] = contrib;
    __syncthreads();
    if (threadIdx.x == 0) {
        float s = 0.0f;
        #pragma unroll
        for (int w = 0; w < WAVES_PER_BLOCK; ++w) s += wsum[w];
        atomicAdd(out, s * neg_inv_b);
    }
}

extern "C" void kernel_launch(void* const* d_in, const int* in_sizes, int n_in,
                              void* d_out, int out_size, void* d_ws, size_t ws_size,
                              hipStream_t stream) {
    const float* u_emb = (const float*)d_in[0];
    const float* v_emb = (const float*)d_in[1];
    const int*   u_pos = (const int*)d_in[2];
    const int*   v_pos = (const int*)d_in[3];
    const int*   v_neg = (const int*)d_in[4];
    float* out = (float*)d_out;

    const int B      = in_sizes[2];           // 16384
    const int vElems = in_sizes[1];           // 100000*128
    float* outp = out;

    hipMemsetAsync(outp, 0, sizeof(float), stream);

    const int pairs  = (B + 1) / 2;
    const int blocks = (pairs + WAVES_PER_BLOCK - 1) / WAVES_PER_BLOCK;

    const size_t needed = (size_t)vElems * sizeof(__half);
    if (ws_size >= needed) {
        __half* v_half = (__half*)d_ws;
        const int n4 = vElems / 4;            // 3.2M uint2 stores
        convert_kernel<<<2048, 256, 0, stream>>>(v_emb, (unsigned int*)v_half, n4);
        skipgram_half_kernel<<<blocks, WAVES_PER_BLOCK * 64, 0, stream>>>(
            u_emb, v_half, u_pos, v_pos, v_neg, outp, B, -1.0f / (float)B);
    } else {
        skipgram_f32_kernel<<<blocks, WAVES_PER_BLOCK * 64, 0, stream>>>(
            u_emb, v_emb, u_pos, v_pos, v_neg, outp, B, -1.0f / (float)B);
    }
}

// Round 6
// 38.284 us; speedup vs baseline: 1.4029x; 1.4029x over previous
//
#include <hip/hip_runtime.h>

// skipgram negative-sampling loss, MI355X.
// R5 falsified the byte/line-wall theory (fp16 halved FETCH, time unchanged)
// -> latency*concurrency bound. This round: 2 waves per row (10 negs each),
// wave-uniform index loads (s_load path), partials to ws (no atomics), and a
// tiny stage-2 for the per-row logsigmoid + final reduction.

constexpr int DIM  = 128;
constexpr int KNEG = 20;
constexpr int WAVES_PER_BLOCK = 4;

__device__ __forceinline__ float log_sigmoid(float x) {
    // stable: min(x,0) - log1p(exp(-|x|))
    return fminf(x, 0.0f) - log1pf(__expf(-fabsf(x)));
}

// ---------- stage 1: per-(row, half-K) partial dots ----------
// task gw: b = gw>>1, c = gw&1. c==0 also computes the positive dot.
// All indices are wave-uniform -> scalar loads; gathers are SGPR-base + lane*8.
__global__ __launch_bounds__(256) void skipgram_stage1(
    const float* __restrict__ u_emb, const float* __restrict__ v_emb,
    const int* __restrict__ u_pos, const int* __restrict__ v_pos,
    const int* __restrict__ v_neg,
    float* __restrict__ pos_arr, float* __restrict__ neg0_arr,
    float* __restrict__ neg1_arr, int B)
{
    const int lane  = threadIdx.x & 63;
    const int wslot = threadIdx.x >> 6;
    const int gw    = blockIdx.x * WAVES_PER_BLOCK + wslot;
    if (gw >= 2 * B) return;

    const int b = gw >> 1;
    const int c = gw & 1;              // wave-uniform

    // uniform scalar loads
    const int up   = u_pos[b];
    const int kbase = b * KNEG + c * 10;
    int idx[10];
    #pragma unroll
    for (int j = 0; j < 10; ++j) idx[j] = v_neg[kbase + j];

    // gathers: each wave reads one 512B row, float2 per lane
    const float2 uu = reinterpret_cast<const float2*>(u_emb + (size_t)up * DIM)[lane];

    float2 vv = make_float2(0.0f, 0.0f);
    if (c == 0) {                      // uniform branch
        const int vp = v_pos[b];
        vv = reinterpret_cast<const float2*>(v_emb + (size_t)vp * DIM)[lane];
    }

    float2 nv[10];
    #pragma unroll
    for (int j = 0; j < 10; ++j)
        nv[j] = reinterpret_cast<const float2*>(v_emb + (size_t)idx[j] * DIM)[lane];

    // compute
    float pos = fmaf(uu.x, vv.x, uu.y * vv.y);     // zero when c==1
    float ax = 0.0f, ay = 0.0f;
    #pragma unroll
    for (int j = 0; j < 10; ++j) { ax += nv[j].x; ay += nv[j].y; }
    float negp = fmaf(uu.x, ax, uu.y * ay);

    // 64-lane butterfly
    #pragma unroll
    for (int off = 32; off; off >>= 1) {
        pos  += __shfl_xor(pos,  off);
        negp += __shfl_xor(negp, off);
    }

    if (lane == 0) {
        if (c == 0) {
            pos_arr[b]  = pos;
            neg0_arr[b] = negp;
        } else {
            neg1_arr[b] = negp;
        }
    }
}

// ---------- stage 2: per-row logsigmoid + global reduction ----------
__global__ __launch_bounds__(256) void skipgram_stage2(
    const float* __restrict__ pos_arr, const float* __restrict__ neg0_arr,
    const float* __restrict__ neg1_arr, float* __restrict__ out,
    int B, float neg_inv_b)
{
    const int i = blockIdx.x * blockDim.x + threadIdx.x;
    const int lane  = threadIdx.x & 63;
    const int wslot = threadIdx.x >> 6;

    float loss = 0.0f;
    if (i < B) {
        float pos = pos_arr[i];
        float neg = neg0_arr[i] + neg1_arr[i];
        loss = log_sigmoid(pos) + log_sigmoid(-neg);
    }

    #pragma unroll
    for (int off = 32; off; off >>= 1) loss += __shfl_xor(loss, off);

    __shared__ float wsum[WAVES_PER_BLOCK];
    if (lane == 0) wsum[wslot] = loss;
    __syncthreads();
    if (threadIdx.x == 0) {
        float s = 0.0f;
        #pragma unroll
        for (int w = 0; w < WAVES_PER_BLOCK; ++w) s += wsum[w];
        atomicAdd(out, s * neg_inv_b);
    }
}

// ---------- fallback: single-kernel f32 (R4 structure) if ws too small ----------
__global__ __launch_bounds__(256) void skipgram_f32_kernel(
    const float* __restrict__ u_emb, const float* __restrict__ v_emb,
    const int* __restrict__ u_pos, const int* __restrict__ v_pos,
    const int* __restrict__ v_neg, float* __restrict__ out,
    int B, float neg_inv_b)
{
    const int lane  = threadIdx.x & 63;
    const int wslot = threadIdx.x >> 6;
    const int half  = lane >> 5;
    const int l32   = lane & 31;
    const int pair  = blockIdx.x * WAVES_PER_BLOCK + wslot;
    const int row   = pair * 2 + half;

    float contrib = 0.0f;
    if (row < B) {
        const int up = u_pos[row];
        const int vp = v_pos[row];
        int idx[KNEG];
        #pragma unroll
        for (int k = 0; k < KNEG; ++k) idx[k] = v_neg[row * KNEG + k];
        const float4 uu = reinterpret_cast<const float4*>(u_emb + (size_t)up * DIM)[l32];
        const float4 vv = reinterpret_cast<const float4*>(v_emb + (size_t)vp * DIM)[l32];
        float pos = fmaf(uu.x, vv.x, fmaf(uu.y, vv.y, fmaf(uu.z, vv.z, uu.w * vv.w)));
        float ax = 0, ay = 0, az = 0, aw = 0;
        #pragma unroll
        for (int k = 0; k < KNEG; ++k) {
            float4 nv = reinterpret_cast<const float4*>(v_emb + (size_t)idx[k] * DIM)[l32];
            ax += nv.x; ay += nv.y; az += nv.z; aw += nv.w;
        }
        float neg = fmaf(uu.x, ax, fmaf(uu.y, ay, fmaf(uu.z, az, uu.w * aw)));
        #pragma unroll
        for (int off = 16; off; off >>= 1) {
            pos += __shfl_xor(pos, off);
            neg += __shfl_xor(neg, off);
        }
        float loss = log_sigmoid(pos) + log_sigmoid(-neg);
        contrib = (l32 == 0) ? loss : 0.0f;
    }
    contrib += __shfl_xor(contrib, 32);
    __shared__ float wsum[WAVES_PER_BLOCK];
    if (lane == 0) wsum[wslot] = contrib;
    __syncthreads();
    if (threadIdx.x == 0) {
        float s = 0.0f;
        #pragma unroll
        for (int w = 0; w < WAVES_PER_BLOCK; ++w) s += wsum[w];
        atomicAdd(out, s * neg_inv_b);
    }
}

extern "C" void kernel_launch(void* const* d_in, const int* in_sizes, int n_in,
                              void* d_out, int out_size, void* d_ws, size_t ws_size,
                              hipStream_t stream) {
    const float* u_emb = (const float*)d_in[0];
    const float* v_emb = (const float*)d_in[1];
    const int*   u_pos = (const int*)d_in[2];
    const int*   v_pos = (const int*)d_in[3];
    const int*   v_neg = (const int*)d_in[4];
    float* out = (float*)d_out;

    const int B = in_sizes[2];            // 16384

    hipMemsetAsync(out, 0, sizeof(float), stream);

    const size_t needed = 3 * (size_t)B * sizeof(float);
    if (ws_size >= needed) {
        float* pos_arr  = (float*)d_ws;
        float* neg0_arr = pos_arr + B;
        float* neg1_arr = neg0_arr + B;

        const int tasks   = 2 * B;                                        // 32768 waves
        const int blocks1 = (tasks + WAVES_PER_BLOCK - 1) / WAVES_PER_BLOCK;  // 8192
        skipgram_stage1<<<blocks1, WAVES_PER_BLOCK * 64, 0, stream>>>(
            u_emb, v_emb, u_pos, v_pos, v_neg, pos_arr, neg0_arr, neg1_arr, B);

        const int blocks2 = (B + 255) / 256;                              // 64
        skipgram_stage2<<<blocks2, 256, 0, stream>>>(
            pos_arr, neg0_arr, neg1_arr, out, B, -1.0f / (float)B);
    } else {
        const int pairs  = (B + 1) / 2;
        const int blocks = (pairs + WAVES_PER_BLOCK - 1) / WAVES_PER_BLOCK;
        skipgram_f32_kernel<<<blocks, WAVES_PER_BLOCK * 64, 0, stream>>>(
            u_emb, v_emb, u_pos, v_pos, v_neg, out, B, -1.0f / (float)B);
    }
}